// Round 3
// baseline (591.410 us; speedup 1.0000x reference)
//
#include <hip/hip_runtime.h>
#include <hip/hip_bf16.h>

typedef unsigned short u16;
typedef short short8_t __attribute__((ext_vector_type(8)));
typedef float f32x4 __attribute__((ext_vector_type(4)));

__device__ __forceinline__ u16 f2bf(float f) {
    union { float f; unsigned int u; } x;
    x.f = f;
    unsigned int r = x.u + 0x7fffu + ((x.u >> 16) & 1u);   // RNE
    return (u16)(r >> 16);
}

// ---------------------------------------------------------------------------
// Kernel 1: gate = h @ WG  [2048 x 8] fp32, top-2 mask, sigmoid -> w[2048][8]
// one wave per token; fully fp32 so top-2 selection matches the reference
// ---------------------------------------------------------------------------
__global__ __launch_bounds__(64) void gate_topk_kernel(
    const float* __restrict__ h, const float* __restrict__ wg, float* __restrict__ w) {
    const int t = blockIdx.x;
    const int lane = threadIdx.x;
    float acc[8];
#pragma unroll
    for (int g = 0; g < 8; ++g) acc[g] = 0.f;
    for (int e = lane; e < 1024; e += 64) {
        float hv = h[(size_t)t * 1024 + e];
        float4 r0 = *(const float4*)&wg[e * 8];
        float4 r1 = *(const float4*)&wg[e * 8 + 4];
        acc[0] += hv * r0.x; acc[1] += hv * r0.y; acc[2] += hv * r0.z; acc[3] += hv * r0.w;
        acc[4] += hv * r1.x; acc[5] += hv * r1.y; acc[6] += hv * r1.z; acc[7] += hv * r1.w;
    }
#pragma unroll
    for (int off = 32; off > 0; off >>= 1) {
#pragma unroll
        for (int g = 0; g < 8; ++g) acc[g] += __shfl_down(acc[g], off);
    }
    if (lane == 0) {
        int i1 = 0;
        for (int g = 1; g < 8; ++g) if (acc[g] > acc[i1]) i1 = g;   // lowest idx on ties
        int i2 = -1;
        for (int g = 0; g < 8; ++g) {
            if (g == i1) continue;
            if (i2 < 0 || acc[g] > acc[i2]) i2 = g;
        }
#pragma unroll
        for (int g = 0; g < 8; ++g) {
            float v = (g == i1 || g == i2) ? (1.f / (1.f + __expf(-acc[g]))) : 0.f;
            w[t * 8 + g] = v;
        }
    }
}

// ---------------------------------------------------------------------------
// Kernel 2: A'[t][g*1024+e] = bf16( w[t][g] * h[t][e] )   ([2048][8192] bf16)
// ---------------------------------------------------------------------------
__global__ __launch_bounds__(256) void build_a_kernel(
    const float* __restrict__ h, const float* __restrict__ w, u16* __restrict__ A) {
    const int t = blockIdx.x;
    const int tid = threadIdx.x;
    float wloc[8];
#pragma unroll
    for (int g = 0; g < 8; ++g) wloc[g] = w[t * 8 + g];
#pragma unroll
    for (int it = 0; it < 4; ++it) {
        int k = (tid + it * 256) * 8;     // 0..8184, step 8
        int g = k >> 10;
        int e = k & 1023;
        float4 v0 = *(const float4*)&h[(size_t)t * 1024 + e];
        float4 v1 = *(const float4*)&h[(size_t)t * 1024 + e + 4];
        float sw = wloc[g];
        u16 outv[8];
        outv[0] = f2bf(v0.x * sw); outv[1] = f2bf(v0.y * sw);
        outv[2] = f2bf(v0.z * sw); outv[3] = f2bf(v0.w * sw);
        outv[4] = f2bf(v1.x * sw); outv[5] = f2bf(v1.y * sw);
        outv[6] = f2bf(v1.z * sw); outv[7] = f2bf(v1.w * sw);
        *(uint4*)&A[(size_t)t * 8192 + k] = *(const uint4*)outv;
    }
}

// ---------------------------------------------------------------------------
// Kernel 3: GEMM  C[M][N] = X[M][K] @ B[K][N]
//   X: bf16 [M][K] (workspace)          -> a_tile[row][k], ds_read_b128 frags
//   B: fp32 [K][N] (model weights)      -> converted to bf16 in-register at
//      staging time -> b_tile[k][n^swz] with ds_write_b64x.. (short8 stores);
//      fragments via 8x ds_read_u16 with XOR swizzle (2 lanes/bank = free).
// 128x128 tile, BK=64, 4 waves of 64x64, 16x16x32 bf16 MFMA.
// RELU2=1: fused relu^2, bf16 out.  RELU2=0: plain fp32 out.
// ---------------------------------------------------------------------------
template <int RELU2>
__global__ __launch_bounds__(256) void gemm_nn_kernel(
    const u16* __restrict__ X, const float* __restrict__ Bm, void* __restrict__ Cout,
    int M, int N, int K) {
    __shared__ short a_tile[128 * 64];   // [row][k]
    __shared__ short b_tile[64 * 128];   // [k][n ^ swz]
    const int tid = threadIdx.x;
    const int lane = tid & 63;
    const int wave = tid >> 6;
    const int m0 = blockIdx.y * 128;
    const int n0 = blockIdx.x * 128;
    const int wm = (wave >> 1) * 64;
    const int wn = (wave & 1) * 64;

    const f32x4 vzero = {0.f, 0.f, 0.f, 0.f};
    f32x4 acc[4][4];
#pragma unroll
    for (int i = 0; i < 4; ++i)
#pragma unroll
        for (int j = 0; j < 4; ++j) acc[i][j] = vzero;

    const int arow = tid >> 3;          // 0..31  (A staging row within 32-row slab)
    const int acol = (tid & 7) * 8;     // 0..56  (A staging k*8)
    const int bk   = tid >> 4;          // 0..15  (B staging k within 16-row slab)
    const int bn   = (tid & 15) * 8;    // 0..120 (B staging n*8)
    const int r    = lane & 15;
    const int quad = lane >> 4;

    for (int kb = 0; kb < K; kb += 64) {
        uint4 av[4];
        float4 bv0[4], bv1[4];
#pragma unroll
        for (int it = 0; it < 4; ++it) {
            av[it]  = *(const uint4*)&X[(size_t)(m0 + arow + it * 32) * K + kb + acol];
            const float* bp = &Bm[(size_t)(kb + bk + it * 16) * N + n0 + bn];
            bv0[it] = *(const float4*)bp;
            bv1[it] = *(const float4*)(bp + 4);
        }
        __syncthreads();   // prior iteration's LDS reads must complete
#pragma unroll
        for (int it = 0; it < 4; ++it) {
            *(short8_t*)&a_tile[(arow + it * 32) * 64 + acol] = *(const short8_t*)&av[it];
            int k = bk + it * 16;
            int nswz = bn ^ (((k >> 3) & 3) << 4);
            u16 bc[8];
            bc[0] = f2bf(bv0[it].x); bc[1] = f2bf(bv0[it].y);
            bc[2] = f2bf(bv0[it].z); bc[3] = f2bf(bv0[it].w);
            bc[4] = f2bf(bv1[it].x); bc[5] = f2bf(bv1[it].y);
            bc[6] = f2bf(bv1[it].z); bc[7] = f2bf(bv1[it].w);
            *(short8_t*)&b_tile[k * 128 + nswz] = *(const short8_t*)bc;
        }
        __syncthreads();
#pragma unroll
        for (int ks = 0; ks < 2; ++ks) {
            short8_t af[4];
#pragma unroll
            for (int i = 0; i < 4; ++i)
                af[i] = *(const short8_t*)&a_tile[(wm + i * 16 + r) * 64 + ks * 32 + quad * 8];
#pragma unroll
            for (int j = 0; j < 4; ++j) {
                // lane holds B[k][n], n = wn+j*16+r, k = ks*32+quad*8+jj
                // stored swizzle for these k is exactly (quad<<4)
                union { u16 s[8]; short8_t v; } bu;
                int nswz = (wn + j * 16 + r) ^ (quad << 4);
#pragma unroll
                for (int jj = 0; jj < 8; ++jj)
                    bu.s[jj] = (u16)b_tile[(ks * 32 + quad * 8 + jj) * 128 + nswz];
#pragma unroll
                for (int i = 0; i < 4; ++i)
                    acc[i][j] = __builtin_amdgcn_mfma_f32_16x16x32_bf16(af[i], bu.v, acc[i][j], 0, 0, 0);
            }
        }
        __syncthreads();
    }

    // epilogue: C/D layout col=lane&15, row=quad*4+reg  (m89/m91 verified)
#pragma unroll
    for (int i = 0; i < 4; ++i)
#pragma unroll
        for (int j = 0; j < 4; ++j) {
#pragma unroll
            for (int reg = 0; reg < 4; ++reg) {
                int cr = m0 + wm + i * 16 + quad * 4 + reg;
                int cc = n0 + wn + j * 16 + r;
                float v = acc[i][j][reg];
                if (RELU2) {
                    v = v > 0.f ? v * v : 0.f;
                    ((u16*)Cout)[(size_t)cr * N + cc] = f2bf(v);
                } else {
                    ((float*)Cout)[(size_t)cr * N + cc] = v;
                }
            }
        }
}

// ---------------------------------------------------------------------------
// Launch — all I/O fp32 (faithful to the jnp.float32 reference)
// ---------------------------------------------------------------------------
extern "C" void kernel_launch(void* const* d_in, const int* in_sizes, int n_in,
                              void* d_out, int out_size, void* d_ws, size_t ws_size,
                              hipStream_t stream) {
    const float* h    = (const float*)d_in[0];   // [2048][1024]
    const float* WG   = (const float*)d_in[1];   // [1024][8]
    const float* Wi   = (const float*)d_in[2];   // [8][1024][4096] = [8192][4096]
    const float* down = (const float*)d_in[3];   // [4096][1024]
    float* out = (float*)d_out;                  // [2048][1024]

    const int T = 2048, H = 1024, I = 4096, G = 8;
    const int K1 = G * H;                        // 8192

    // workspace layout (48.07 MiB total)
    char* ws = (char*)d_ws;
    float* w_gate = (float*)(ws);                      // 2048*8*4    = 64 KiB
    u16*   Aprime = (u16*)(ws + 65536);                // 2048*8192*2 = 32 MiB
    u16*   act    = (u16*)(ws + 65536 + 33554432);     // 2048*4096*2 = 16 MiB

    // 1. gates + top-2 sigmoid weights (fp32 exact)
    gate_topk_kernel<<<T, 64, 0, stream>>>(h, WG, w_gate);

    // 2. A' = w-scaled hidden, replicated per group  [2048][8192] bf16
    build_a_kernel<<<T, 256, 0, stream>>>(h, w_gate, Aprime);

    // 3. up = A' @ Wi (fp32 weights converted at staging), fused relu^2 -> act bf16
    gemm_nn_kernel<1><<<dim3(I / 128, T / 128), 256, 0, stream>>>(Aprime, Wi, (void*)act, T, I, K1);

    // 4. out = act @ down -> fp32
    gemm_nn_kernel<0><<<dim3(H / 128, T / 128), 256, 0, stream>>>(act, down, (void*)out, T, H, I);
}

// Round 4
// 531.375 us; speedup vs baseline: 1.1130x; 1.1130x over previous
//
#include <hip/hip_runtime.h>
#include <hip/hip_bf16.h>

typedef unsigned short u16;
typedef short short8_t __attribute__((ext_vector_type(8)));
typedef float f32x4 __attribute__((ext_vector_type(4)));

__device__ __forceinline__ u16 f2bf(float f) {
    union { float f; unsigned int u; } x;
    x.f = f;
    unsigned int r = x.u + 0x7fffu + ((x.u >> 16) & 1u);   // RNE
    return (u16)(r >> 16);
}

// ---------------------------------------------------------------------------
// Kernel 1: gate = h @ WG  [2048 x 8] fp32, top-2 mask, sigmoid -> w[2048][8]
// ---------------------------------------------------------------------------
__global__ __launch_bounds__(64) void gate_topk_kernel(
    const float* __restrict__ h, const float* __restrict__ wg, float* __restrict__ w) {
    const int t = blockIdx.x;
    const int lane = threadIdx.x;
    float acc[8];
#pragma unroll
    for (int g = 0; g < 8; ++g) acc[g] = 0.f;
    for (int e = lane; e < 1024; e += 64) {
        float hv = h[(size_t)t * 1024 + e];
        float4 r0 = *(const float4*)&wg[e * 8];
        float4 r1 = *(const float4*)&wg[e * 8 + 4];
        acc[0] += hv * r0.x; acc[1] += hv * r0.y; acc[2] += hv * r0.z; acc[3] += hv * r0.w;
        acc[4] += hv * r1.x; acc[5] += hv * r1.y; acc[6] += hv * r1.z; acc[7] += hv * r1.w;
    }
#pragma unroll
    for (int off = 32; off > 0; off >>= 1) {
#pragma unroll
        for (int g = 0; g < 8; ++g) acc[g] += __shfl_down(acc[g], off);
    }
    if (lane == 0) {
        int i1 = 0;
        for (int g = 1; g < 8; ++g) if (acc[g] > acc[i1]) i1 = g;   // lowest idx on ties
        int i2 = -1;
        for (int g = 0; g < 8; ++g) {
            if (g == i1) continue;
            if (i2 < 0 || acc[g] > acc[i2]) i2 = g;
        }
#pragma unroll
        for (int g = 0; g < 8; ++g) {
            float v = (g == i1 || g == i2) ? (1.f / (1.f + __expf(-acc[g]))) : 0.f;
            w[t * 8 + g] = v;
        }
    }
}

// ---------------------------------------------------------------------------
// Kernel 2: A'[t][g*1024+e] = bf16( w[t][g] * h[t][e] )   ([2048][8192] bf16)
// ---------------------------------------------------------------------------
__global__ __launch_bounds__(256) void build_a_kernel(
    const float* __restrict__ h, const float* __restrict__ w, u16* __restrict__ A) {
    const int t = blockIdx.x;
    const int tid = threadIdx.x;
    float wloc[8];
#pragma unroll
    for (int g = 0; g < 8; ++g) wloc[g] = w[t * 8 + g];
#pragma unroll
    for (int it = 0; it < 4; ++it) {
        int k = (tid + it * 256) * 8;     // 0..8184, step 8
        int g = k >> 10;
        int e = k & 1023;
        float4 v0 = *(const float4*)&h[(size_t)t * 1024 + e];
        float4 v1 = *(const float4*)&h[(size_t)t * 1024 + e + 4];
        float sw = wloc[g];
        u16 outv[8];
        outv[0] = f2bf(v0.x * sw); outv[1] = f2bf(v0.y * sw);
        outv[2] = f2bf(v0.z * sw); outv[3] = f2bf(v0.w * sw);
        outv[4] = f2bf(v1.x * sw); outv[5] = f2bf(v1.y * sw);
        outv[6] = f2bf(v1.z * sw); outv[7] = f2bf(v1.w * sw);
        *(uint4*)&A[(size_t)t * 8192 + k] = *(const uint4*)outv;
    }
}

// ---------------------------------------------------------------------------
// Kernel 3: GEMM  C[M][N] = X[M][K] @ B[K][N]
//   X: bf16 [M][K]; B: fp32 [K][N] converted to bf16 during staging.
//   LDS: both tiles [row][64k] shorts (row = m for A, n for B), 16B chunks
//   XOR-swizzled: chunk k8 stored at position (k8 ^ (row&7)). Every LDS
//   access is b128 at the 8-lane/4-bank HW floor (no conflicts beyond the
//   1024B/access minimum). B staged via 8 k-strided, lane-coalesced dword
//   loads per chunk. XCD-aware block swizzle: same-N-slab blocks on one XCD.
//   BMxBN tile, BK=64, 4 waves in WROWSxWCOLS grid, 16x16x32 bf16 MFMA.
// ---------------------------------------------------------------------------
template <int BM, int BN, int WROWS, int WCOLS, int RELU2>
__global__ __launch_bounds__(256) void gemm_nn_kernel(
    const u16* __restrict__ X, const float* __restrict__ Bm, void* __restrict__ Cout,
    int M, int N, int K) {
    constexpr int WM = BM / WROWS;      // wave tile rows
    constexpr int WN = BN / WCOLS;      // wave tile cols
    constexpr int FI = WM / 16;
    constexpr int FJ = WN / 16;
    constexpr int NA = BM * 8 / 256;    // A 16B-chunks per thread
    constexpr int NB = BN * 8 / 256;    // B 16B-chunks per thread
    __shared__ short a_tile[BM * 64];
    __shared__ short b_tile[BN * 64];
    const int tid = threadIdx.x;
    const int lane = tid & 63;
    const int wave = tid >> 6;

    // XCD-aware remap: dispatch id lid -> xcd = lid%8 (observed round-robin).
    // All blocks of one n_tile land on one XCD; m_tile varies fastest.
    const int Nt = gridDim.x, Mt = gridDim.y;
    const int lid = blockIdx.y * Nt + blockIdx.x;
    const int xcd = lid & 7;
    const int p = lid >> 3;
    const int n_tile = xcd * (Nt >> 3) + p / Mt;
    const int m_tile = p % Mt;
    const int m0 = m_tile * BM;
    const int n0 = n_tile * BN;

    const int wm = (wave / WCOLS) * WM;
    const int wn = (wave % WCOLS) * WN;
    const int r = lane & 15;
    const int quad = lane >> 4;

    const f32x4 vzero = {0.f, 0.f, 0.f, 0.f};
    f32x4 acc[FI][FJ];
#pragma unroll
    for (int i = 0; i < FI; ++i)
#pragma unroll
        for (int j = 0; j < FJ; ++j) acc[i][j] = vzero;

    for (int kb = 0; kb < K; kb += 64) {
        // ---- global loads into registers ----
        uint4 av[NA];
#pragma unroll
        for (int ca = 0; ca < NA; ++ca) {
            int idx = ca * 256 + tid;
            int ar = idx >> 3;          // row (m)
            int ak8 = idx & 7;          // 16B chunk within row
            av[ca] = *(const uint4*)&X[(size_t)(m0 + ar) * K + kb + ak8 * 8];
        }
        float bv[NB][8];
#pragma unroll
        for (int cb = 0; cb < NB; ++cb) {
            int idx = cb * 256 + tid;
            int bn_ = idx % BN;         // n within tile (lane-fastest -> coalesced)
            int bk8 = idx / BN;         // k chunk
            const float* bp = Bm + (size_t)(kb + bk8 * 8) * N + n0 + bn_;
#pragma unroll
            for (int kk = 0; kk < 8; ++kk) bv[cb][kk] = bp[(size_t)kk * N];
        }
        __syncthreads();   // prior iteration's LDS reads must complete
        // ---- LDS stores (swizzled b128) ----
#pragma unroll
        for (int ca = 0; ca < NA; ++ca) {
            int idx = ca * 256 + tid;
            int ar = idx >> 3;
            int ak8 = idx & 7;
            *(short8_t*)&a_tile[ar * 64 + ((ak8 ^ (ar & 7)) * 8)] = *(const short8_t*)&av[ca];
        }
#pragma unroll
        for (int cb = 0; cb < NB; ++cb) {
            int idx = cb * 256 + tid;
            int bn_ = idx % BN;
            int bk8 = idx / BN;
            u16 bc[8];
#pragma unroll
            for (int kk = 0; kk < 8; ++kk) bc[kk] = f2bf(bv[cb][kk]);
            *(short8_t*)&b_tile[bn_ * 64 + ((bk8 ^ (bn_ & 7)) * 8)] = *(const short8_t*)bc;
        }
        __syncthreads();
        // ---- MFMA ----
#pragma unroll
        for (int ks = 0; ks < 2; ++ks) {
            const int cp = (ks * 4 + quad) ^ (r & 7);   // swizzled chunk position
            short8_t af[FI], bfr[FJ];
#pragma unroll
            for (int i = 0; i < FI; ++i)
                af[i] = *(const short8_t*)&a_tile[(wm + i * 16 + r) * 64 + cp * 8];
#pragma unroll
            for (int j = 0; j < FJ; ++j)
                bfr[j] = *(const short8_t*)&b_tile[(wn + j * 16 + r) * 64 + cp * 8];
#pragma unroll
            for (int i = 0; i < FI; ++i)
#pragma unroll
                for (int j = 0; j < FJ; ++j)
                    acc[i][j] = __builtin_amdgcn_mfma_f32_16x16x32_bf16(af[i], bfr[j], acc[i][j], 0, 0, 0);
        }
        __syncthreads();
    }

    // epilogue: C/D layout col=lane&15, row=quad*4+reg  (m89/m91 verified)
#pragma unroll
    for (int i = 0; i < FI; ++i)
#pragma unroll
        for (int j = 0; j < FJ; ++j) {
#pragma unroll
            for (int reg = 0; reg < 4; ++reg) {
                int cr = m0 + wm + i * 16 + quad * 4 + reg;
                int cc = n0 + wn + j * 16 + r;
                float v = acc[i][j][reg];
                if (RELU2) {
                    v = v > 0.f ? v * v : 0.f;
                    ((u16*)Cout)[(size_t)cr * N + cc] = f2bf(v);
                } else {
                    ((float*)Cout)[(size_t)cr * N + cc] = v;
                }
            }
        }
}

// ---------------------------------------------------------------------------
// Launch — all I/O fp32
// ---------------------------------------------------------------------------
extern "C" void kernel_launch(void* const* d_in, const int* in_sizes, int n_in,
                              void* d_out, int out_size, void* d_ws, size_t ws_size,
                              hipStream_t stream) {
    const float* h    = (const float*)d_in[0];   // [2048][1024]
    const float* WG   = (const float*)d_in[1];   // [1024][8]
    const float* Wi   = (const float*)d_in[2];   // [8][1024][4096] = [8192][4096]
    const float* down = (const float*)d_in[3];   // [4096][1024]
    float* out = (float*)d_out;                  // [2048][1024]

    const int T = 2048, H = 1024, I = 4096, G = 8;
    const int K1 = G * H;                        // 8192

    // workspace layout (48.07 MiB total — proven to fit)
    char* ws = (char*)d_ws;
    float* w_gate = (float*)(ws);                      // 2048*8*4    = 64 KiB
    u16*   Aprime = (u16*)(ws + 65536);                // 2048*8192*2 = 32 MiB
    u16*   act    = (u16*)(ws + 65536 + 33554432);     // 2048*4096*2 = 16 MiB

    // 1. gates + top-2 sigmoid weights (fp32 exact)
    gate_topk_kernel<<<T, 64, 0, stream>>>(h, WG, w_gate);

    // 2. A' = w-scaled hidden, replicated per group  [2048][8192] bf16
    build_a_kernel<<<T, 256, 0, stream>>>(h, w_gate, Aprime);

    // 3. up = A' @ Wi, fused relu^2 -> act bf16   (512 blocks, 128x128)
    gemm_nn_kernel<128, 128, 2, 2, 1><<<dim3(I / 128, T / 128), 256, 0, stream>>>(
        Aprime, Wi, (void*)act, T, I, K1);

    // 4. out = act @ down -> fp32                 (256 blocks, 64x128)
    gemm_nn_kernel<64, 128, 1, 4, 0><<<dim3(H / 128, T / 64), 256, 0, stream>>>(
        act, down, (void*)out, T, H, I);
}

// Round 5
// 497.346 us; speedup vs baseline: 1.1891x; 1.0684x over previous
//
#include <hip/hip_runtime.h>
#include <hip/hip_bf16.h>

typedef unsigned short u16;
typedef short short8_t __attribute__((ext_vector_type(8)));
typedef float f32x4 __attribute__((ext_vector_type(4)));

#define GLOBAL_AS(p) ((const __attribute__((address_space(1))) void*)(p))
#define LDS_AS(p)    ((__attribute__((address_space(3))) void*)(p))

__device__ __forceinline__ u16 f2bf(float f) {
    union { float f; unsigned int u; } x;
    x.f = f;
    unsigned int r = x.u + 0x7fffu + ((x.u >> 16) & 1u);   // RNE
    return (u16)(r >> 16);
}

// ---------------------------------------------------------------------------
// Kernel 1: gate = h @ WG  [2048 x 8] fp32, top-2 mask, sigmoid -> w[2048][8]
// ---------------------------------------------------------------------------
__global__ __launch_bounds__(64) void gate_topk_kernel(
    const float* __restrict__ h, const float* __restrict__ wg, float* __restrict__ w) {
    const int t = blockIdx.x;
    const int lane = threadIdx.x;
    float acc[8];
#pragma unroll
    for (int g = 0; g < 8; ++g) acc[g] = 0.f;
    for (int e = lane; e < 1024; e += 64) {
        float hv = h[(size_t)t * 1024 + e];
        float4 r0 = *(const float4*)&wg[e * 8];
        float4 r1 = *(const float4*)&wg[e * 8 + 4];
        acc[0] += hv * r0.x; acc[1] += hv * r0.y; acc[2] += hv * r0.z; acc[3] += hv * r0.w;
        acc[4] += hv * r1.x; acc[5] += hv * r1.y; acc[6] += hv * r1.z; acc[7] += hv * r1.w;
    }
#pragma unroll
    for (int off = 32; off > 0; off >>= 1) {
#pragma unroll
        for (int g = 0; g < 8; ++g) acc[g] += __shfl_down(acc[g], off);
    }
    if (lane == 0) {
        int i1 = 0;
        for (int g = 1; g < 8; ++g) if (acc[g] > acc[i1]) i1 = g;   // lowest idx on ties
        int i2 = -1;
        for (int g = 0; g < 8; ++g) {
            if (g == i1) continue;
            if (i2 < 0 || acc[g] > acc[i2]) i2 = g;
        }
#pragma unroll
        for (int g = 0; g < 8; ++g) {
            float v = (g == i1 || g == i2) ? (1.f / (1.f + __expf(-acc[g]))) : 0.f;
            w[t * 8 + g] = v;
        }
    }
}

// ---------------------------------------------------------------------------
// Kernel 2: A'[t][g*1024+e] = bf16( w[t][g] * h[t][e] )   ([2048][8192] bf16)
// ---------------------------------------------------------------------------
__global__ __launch_bounds__(256) void build_a_kernel(
    const float* __restrict__ h, const float* __restrict__ w, u16* __restrict__ A) {
    const int t = blockIdx.x;
    const int tid = threadIdx.x;
    float wloc[8];
#pragma unroll
    for (int g = 0; g < 8; ++g) wloc[g] = w[t * 8 + g];
#pragma unroll
    for (int it = 0; it < 4; ++it) {
        int k = (tid + it * 256) * 8;
        int g = k >> 10;
        int e = k & 1023;
        float4 v0 = *(const float4*)&h[(size_t)t * 1024 + e];
        float4 v1 = *(const float4*)&h[(size_t)t * 1024 + e + 4];
        float sw = wloc[g];
        u16 outv[8];
        outv[0] = f2bf(v0.x * sw); outv[1] = f2bf(v0.y * sw);
        outv[2] = f2bf(v0.z * sw); outv[3] = f2bf(v0.w * sw);
        outv[4] = f2bf(v1.x * sw); outv[5] = f2bf(v1.y * sw);
        outv[6] = f2bf(v1.z * sw); outv[7] = f2bf(v1.w * sw);
        *(uint4*)&A[(size_t)t * 8192 + k] = *(const uint4*)outv;
    }
}

// ---------------------------------------------------------------------------
// Kernel T: transpose + fp32->bf16  in[R][C] fp32 -> out[C][R] bf16
// ---------------------------------------------------------------------------
__global__ __launch_bounds__(256) void transpose_cvt_kernel(
    const float* __restrict__ in, u16* __restrict__ out, int R, int C) {
    __shared__ u16 tile[64][65];
    const int rt = blockIdx.y * 64;
    const int ct = blockIdx.x * 64;
    const int tid = threadIdx.x;
#pragma unroll
    for (int it = 0; it < 2; ++it) {
        int r = (tid >> 3) + it * 32;
        int c8 = (tid & 7) * 8;
        const float* ip = &in[(size_t)(rt + r) * C + ct + c8];
        float4 v0 = *(const float4*)ip;
        float4 v1 = *(const float4*)(ip + 4);
        tile[c8 + 0][r] = f2bf(v0.x); tile[c8 + 1][r] = f2bf(v0.y);
        tile[c8 + 2][r] = f2bf(v0.z); tile[c8 + 3][r] = f2bf(v0.w);
        tile[c8 + 4][r] = f2bf(v1.x); tile[c8 + 5][r] = f2bf(v1.y);
        tile[c8 + 6][r] = f2bf(v1.z); tile[c8 + 7][r] = f2bf(v1.w);
    }
    __syncthreads();
#pragma unroll
    for (int it = 0; it < 2; ++it) {
        int c = (tid >> 3) + it * 32;
        int r8 = (tid & 7) * 8;
        u16 tmp[8];
#pragma unroll
        for (int j = 0; j < 8; ++j) tmp[j] = tile[c][r8 + j];
        *(uint4*)&out[(size_t)(ct + c) * R + rt + r8] = *(const uint4*)tmp;
    }
}

// ---------------------------------------------------------------------------
// Kernel G (main path): GEMM  C[M][N] = X[M][K] @ Y^T, both bf16 [row][K].
// m97 structure: BMx128 tile, BK=64, global_load_lds width=16, unswizzled
// [row][64] LDS tiles, 16x16x32 bf16 MFMA. XCD-aware block swizzle.
// ---------------------------------------------------------------------------
template <int BM, int WROWS, int WCOLS, int RELU2>
__global__ __launch_bounds__(256) void gemm_tn_kernel(
    const u16* __restrict__ X, const u16* __restrict__ Y, void* __restrict__ Cout,
    int M, int N, int K) {
    constexpr int WM = BM / WROWS;
    constexpr int WN = 128 / WCOLS;
    constexpr int FI = WM / 16;
    constexpr int FJ = WN / 16;
    __shared__ short a_tile[BM * 64];
    __shared__ short b_tile[128 * 64];
    const int tid = threadIdx.x;
    const int lane = tid & 63;
    const int wave = tid >> 6;

    // XCD-aware remap: same n_tile -> same XCD; m_tile varies fastest.
    const int Nt = gridDim.x, Mt = gridDim.y;
    const int lid = blockIdx.y * Nt + blockIdx.x;
    const int xcd = lid & 7;
    const int p = lid >> 3;
    const int n_tile = xcd * (Nt >> 3) + p / Mt;
    const int m_tile = p % Mt;
    const int m0 = m_tile * BM;
    const int n0 = n_tile * 128;

    const int wm = (wave / WCOLS) * WM;
    const int wn = (wave % WCOLS) * WN;
    const int rowin = lane >> 3;
    const int col8 = (lane & 7) * 8;
    const int r = lane & 15;
    const int quad = lane >> 4;

    const f32x4 vzero = {0.f, 0.f, 0.f, 0.f};
    f32x4 acc[FI][FJ];
#pragma unroll
    for (int i = 0; i < FI; ++i)
#pragma unroll
        for (int j = 0; j < FJ; ++j) acc[i][j] = vzero;

    for (int kb = 0; kb < K; kb += 64) {
        // async global -> LDS staging, 16B/lane, 8 rows per instruction
#pragma unroll
        for (int it = 0; it < BM / 32; ++it) {
            int row = wave * 8 + it * 32 + rowin;
            const u16* ga = X + (size_t)(m0 + row) * K + kb + col8;
            __builtin_amdgcn_global_load_lds(GLOBAL_AS(ga), LDS_AS(&a_tile[row * 64 + col8]), 16, 0, 0);
        }
#pragma unroll
        for (int it = 0; it < 4; ++it) {
            int row = wave * 8 + it * 32 + rowin;
            const u16* gb = Y + (size_t)(n0 + row) * K + kb + col8;
            __builtin_amdgcn_global_load_lds(GLOBAL_AS(gb), LDS_AS(&b_tile[row * 64 + col8]), 16, 0, 0);
        }
        __syncthreads();
#pragma unroll
        for (int ks = 0; ks < 2; ++ks) {
            short8_t af[FI], bfr[FJ];
#pragma unroll
            for (int i = 0; i < FI; ++i)
                af[i] = *(const short8_t*)&a_tile[(wm + i * 16 + r) * 64 + ks * 32 + quad * 8];
#pragma unroll
            for (int j = 0; j < FJ; ++j)
                bfr[j] = *(const short8_t*)&b_tile[(wn + j * 16 + r) * 64 + ks * 32 + quad * 8];
#pragma unroll
            for (int i = 0; i < FI; ++i)
#pragma unroll
                for (int j = 0; j < FJ; ++j)
                    acc[i][j] = __builtin_amdgcn_mfma_f32_16x16x32_bf16(af[i], bfr[j], acc[i][j], 0, 0, 0);
        }
        __syncthreads();
    }

    // epilogue: C/D layout col=lane&15, row=quad*4+reg
#pragma unroll
    for (int i = 0; i < FI; ++i)
#pragma unroll
        for (int j = 0; j < FJ; ++j) {
#pragma unroll
            for (int reg = 0; reg < 4; ++reg) {
                int cr = m0 + wm + i * 16 + quad * 4 + reg;
                int cc = n0 + wn + j * 16 + r;
                float v = acc[i][j][reg];
                if (RELU2) {
                    v = v > 0.f ? v * v : 0.f;
                    ((u16*)Cout)[(size_t)cr * N + cc] = f2bf(v);
                } else {
                    ((float*)Cout)[(size_t)cr * N + cc] = v;
                }
            }
        }
}

// ---------------------------------------------------------------------------
// Fallback GEMM (round-4, proven): C = X(bf16 [M][K]) @ B(fp32 [K][N])
// ---------------------------------------------------------------------------
template <int BM, int BN, int WROWS, int WCOLS, int RELU2>
__global__ __launch_bounds__(256) void gemm_nn_kernel(
    const u16* __restrict__ X, const float* __restrict__ Bm, void* __restrict__ Cout,
    int M, int N, int K) {
    constexpr int WM = BM / WROWS;
    constexpr int WN = BN / WCOLS;
    constexpr int FI = WM / 16;
    constexpr int FJ = WN / 16;
    constexpr int NA = BM * 8 / 256;
    constexpr int NB = BN * 8 / 256;
    __shared__ short a_tile[BM * 64];
    __shared__ short b_tile[BN * 64];
    const int tid = threadIdx.x;
    const int lane = tid & 63;
    const int wave = tid >> 6;
    const int Nt = gridDim.x, Mt = gridDim.y;
    const int lid = blockIdx.y * Nt + blockIdx.x;
    const int xcd = lid & 7;
    const int p = lid >> 3;
    const int n_tile = xcd * (Nt >> 3) + p / Mt;
    const int m_tile = p % Mt;
    const int m0 = m_tile * BM;
    const int n0 = n_tile * BN;
    const int wm = (wave / WCOLS) * WM;
    const int wn = (wave % WCOLS) * WN;
    const int r = lane & 15;
    const int quad = lane >> 4;
    const f32x4 vzero = {0.f, 0.f, 0.f, 0.f};
    f32x4 acc[FI][FJ];
#pragma unroll
    for (int i = 0; i < FI; ++i)
#pragma unroll
        for (int j = 0; j < FJ; ++j) acc[i][j] = vzero;

    for (int kb = 0; kb < K; kb += 64) {
        uint4 av[NA];
#pragma unroll
        for (int ca = 0; ca < NA; ++ca) {
            int idx = ca * 256 + tid;
            av[ca] = *(const uint4*)&X[(size_t)(m0 + (idx >> 3)) * K + kb + (idx & 7) * 8];
        }
        float bv[NB][8];
#pragma unroll
        for (int cb = 0; cb < NB; ++cb) {
            int idx = cb * 256 + tid;
            int bn_ = idx % BN;
            int bk8 = idx / BN;
            const float* bp = Bm + (size_t)(kb + bk8 * 8) * N + n0 + bn_;
#pragma unroll
            for (int kk = 0; kk < 8; ++kk) bv[cb][kk] = bp[(size_t)kk * N];
        }
        __syncthreads();
#pragma unroll
        for (int ca = 0; ca < NA; ++ca) {
            int idx = ca * 256 + tid;
            int ar = idx >> 3;
            int ak8 = idx & 7;
            *(short8_t*)&a_tile[ar * 64 + ((ak8 ^ (ar & 7)) * 8)] = *(const short8_t*)&av[ca];
        }
#pragma unroll
        for (int cb = 0; cb < NB; ++cb) {
            int idx = cb * 256 + tid;
            int bn_ = idx % BN;
            int bk8 = idx / BN;
            u16 bc[8];
#pragma unroll
            for (int kk = 0; kk < 8; ++kk) bc[kk] = f2bf(bv[cb][kk]);
            *(short8_t*)&b_tile[bn_ * 64 + ((bk8 ^ (bn_ & 7)) * 8)] = *(const short8_t*)bc;
        }
        __syncthreads();
#pragma unroll
        for (int ks = 0; ks < 2; ++ks) {
            const int cp = (ks * 4 + quad) ^ (r & 7);
            short8_t af[FI], bfr[FJ];
#pragma unroll
            for (int i = 0; i < FI; ++i)
                af[i] = *(const short8_t*)&a_tile[(wm + i * 16 + r) * 64 + cp * 8];
#pragma unroll
            for (int j = 0; j < FJ; ++j)
                bfr[j] = *(const short8_t*)&b_tile[(wn + j * 16 + r) * 64 + cp * 8];
#pragma unroll
            for (int i = 0; i < FI; ++i)
#pragma unroll
                for (int j = 0; j < FJ; ++j)
                    acc[i][j] = __builtin_amdgcn_mfma_f32_16x16x32_bf16(af[i], bfr[j], acc[i][j], 0, 0, 0);
        }
        __syncthreads();
    }
#pragma unroll
    for (int i = 0; i < FI; ++i)
#pragma unroll
        for (int j = 0; j < FJ; ++j) {
#pragma unroll
            for (int reg = 0; reg < 4; ++reg) {
                int cr = m0 + wm + i * 16 + quad * 4 + reg;
                int cc = n0 + wn + j * 16 + r;
                float v = acc[i][j][reg];
                if (RELU2) {
                    v = v > 0.f ? v * v : 0.f;
                    ((u16*)Cout)[(size_t)cr * N + cc] = f2bf(v);
                } else {
                    ((float*)Cout)[(size_t)cr * N + cc] = v;
                }
            }
        }
}

// ---------------------------------------------------------------------------
// Launch
// ---------------------------------------------------------------------------
extern "C" void kernel_launch(void* const* d_in, const int* in_sizes, int n_in,
                              void* d_out, int out_size, void* d_ws, size_t ws_size,
                              hipStream_t stream) {
    const float* h    = (const float*)d_in[0];   // [2048][1024]
    const float* WG   = (const float*)d_in[1];   // [1024][8]
    const float* Wi   = (const float*)d_in[2];   // [8192][4096]
    const float* down = (const float*)d_in[3];   // [4096][1024]
    float* out = (float*)d_out;                  // [2048][1024]

    const int T = 2048, H = 1024, I = 4096, G = 8;
    const int K1 = G * H;                        // 8192

    // workspace layout
    char* ws = (char*)d_ws;
    float* w_gate = (float*)(ws);                              // 64 KiB
    u16*   Aprime = (u16*)(ws + 65536);                        // 32 MiB
    u16*   act    = (u16*)(ws + 65536 + 33554432);             // 16 MiB
    u16*   WiT    = (u16*)(ws + 65536 + 33554432 + 16777216);  // 64 MiB [4096][8192]
    u16*   downT  = (u16*)(ws + 65536 + 33554432 + 16777216 + 67108864); // 8 MiB [1024][4096]
    const size_t WS_NEEDED = 65536ULL + 33554432 + 16777216 + 67108864 + 8388608;

    gate_topk_kernel<<<T, 64, 0, stream>>>(h, WG, w_gate);
    build_a_kernel<<<T, 256, 0, stream>>>(h, w_gate, Aprime);

    if (ws_size >= WS_NEEDED) {
        // main path: pre-transpose+convert weights, m97-style TN GEMMs
        transpose_cvt_kernel<<<dim3(I / 64, K1 / 64), 256, 0, stream>>>(Wi, WiT, K1, I);
        transpose_cvt_kernel<<<dim3(H / 64, I / 64), 256, 0, stream>>>(down, downT, I, H);
        gemm_tn_kernel<128, 2, 2, 1><<<dim3(I / 128, T / 128), 256, 0, stream>>>(
            Aprime, WiT, (void*)act, T, I, K1);
        gemm_tn_kernel<64, 1, 4, 0><<<dim3(H / 128, T / 64), 256, 0, stream>>>(
            act, downT, (void*)out, T, H, I);
    } else {
        // fallback: round-4 proven path (48 MiB ws)
        gemm_nn_kernel<128, 128, 2, 2, 1><<<dim3(I / 128, T / 128), 256, 0, stream>>>(
            Aprime, Wi, (void*)act, T, I, K1);
        gemm_nn_kernel<64, 128, 1, 4, 0><<<dim3(H / 128, T / 64), 256, 0, stream>>>(
            act, down, (void*)out, T, H, I);
    }
}

// Round 6
// 374.231 us; speedup vs baseline: 1.5803x; 1.3290x over previous
//
#include <hip/hip_runtime.h>
#include <hip/hip_bf16.h>

typedef unsigned short u16;
typedef short short8_t __attribute__((ext_vector_type(8)));
typedef float f32x4 __attribute__((ext_vector_type(4)));

#define GLOBAL_AS(p) ((const __attribute__((address_space(1))) void*)(p))
#define LDS_AS(p)    ((__attribute__((address_space(3))) void*)(p))

__device__ __forceinline__ u16 f2bf(float f) {
    union { float f; unsigned int u; } x;
    x.f = f;
    unsigned int r = x.u + 0x7fffu + ((x.u >> 16) & 1u);   // RNE
    return (u16)(r >> 16);
}

// meta layout (ints), fits in 64 KiB:
//  [0] n_mtiles   [1] total_padded_rows
//  [2..42)   tile_expert
//  [42..82)  tile_base_row
//  [96..96+4096)   pair_row[t*2+j]  (row index of token t's j-th expert)
//  [4192..9312)    row_tok[row]     (token id, -1 = pad)
//  [9312..14432)   row_w[row]       (float weight)
#define M_NMT   0
#define M_TE    2
#define M_TB    42
#define M_PAIR  96
#define M_RTOK  4192
#define M_RW    9312

// ---------------------------------------------------------------------------
// Kernel 1: gate = h @ WG, top-2 sigmoid weights -> w[2048][8] fp32
// ---------------------------------------------------------------------------
__global__ __launch_bounds__(64) void gate_topk_kernel(
    const float* __restrict__ h, const float* __restrict__ wg, float* __restrict__ w) {
    const int t = blockIdx.x;
    const int lane = threadIdx.x;
    float acc[8];
#pragma unroll
    for (int g = 0; g < 8; ++g) acc[g] = 0.f;
    for (int e = lane; e < 1024; e += 64) {
        float hv = h[(size_t)t * 1024 + e];
        float4 r0 = *(const float4*)&wg[e * 8];
        float4 r1 = *(const float4*)&wg[e * 8 + 4];
        acc[0] += hv * r0.x; acc[1] += hv * r0.y; acc[2] += hv * r0.z; acc[3] += hv * r0.w;
        acc[4] += hv * r1.x; acc[5] += hv * r1.y; acc[6] += hv * r1.z; acc[7] += hv * r1.w;
    }
#pragma unroll
    for (int off = 32; off > 0; off >>= 1) {
#pragma unroll
        for (int g = 0; g < 8; ++g) acc[g] += __shfl_down(acc[g], off);
    }
    if (lane == 0) {
        int i1 = 0;
        for (int g = 1; g < 8; ++g) if (acc[g] > acc[i1]) i1 = g;   // lowest idx on ties
        int i2 = -1;
        for (int g = 0; g < 8; ++g) {
            if (g == i1) continue;
            if (i2 < 0 || acc[g] > acc[i2]) i2 = g;
        }
#pragma unroll
        for (int g = 0; g < 8; ++g) {
            float v = (g == i1 || g == i2) ? (1.f / (1.f + __expf(-acc[g]))) : 0.f;
            w[t * 8 + g] = v;
        }
    }
}

// ---------------------------------------------------------------------------
// Kernel 2: scan — per-expert counts, 128-padded offsets, tile table, row maps
// single block, 256 threads
// ---------------------------------------------------------------------------
__global__ __launch_bounds__(256) void scan_kernel(
    const float* __restrict__ w, int* __restrict__ meta) {
    __shared__ int cnt[8], pos[8];
    const int tid = threadIdx.x;
    if (tid < 8) cnt[tid] = 0;
    __syncthreads();
    for (int t = tid; t < 2048; t += 256) {
#pragma unroll
        for (int g = 0; g < 8; ++g)
            if (w[t * 8 + g] > 0.f) atomicAdd(&cnt[g], 1);
    }
    __syncthreads();
    if (tid == 0) {
        int base = 0, mt = 0;
        for (int e = 0; e < 8; ++e) {
            pos[e] = base;
            int nt = (cnt[e] + 127) >> 7;
            for (int k = 0; k < nt; ++k) { meta[M_TE + mt] = e; meta[M_TB + mt] = base + k * 128; ++mt; }
            base += nt << 7;
        }
        meta[M_NMT] = mt;
        meta[1] = base;
    }
    __syncthreads();
    for (int i = tid; i < 5120; i += 256) meta[M_RTOK + i] = -1;
    __syncthreads();
    float* row_w = (float*)&meta[M_RW];
    for (int t = tid; t < 2048; t += 256) {
        int slot = 0;
#pragma unroll
        for (int g = 0; g < 8; ++g) {
            float wv = w[t * 8 + g];
            if (wv > 0.f) {
                int p = atomicAdd(&pos[g], 1);
                meta[M_RTOK + p] = t;
                row_w[p] = wv;
                meta[M_PAIR + t * 2 + slot] = p;
                ++slot;
            }
        }
    }
}

// ---------------------------------------------------------------------------
// Kernel 3: gather A rows — A[row] = bf16(w_row * h[tok]); pad rows -> 0
// grid 5120 blocks x 256 threads, one row/block
// ---------------------------------------------------------------------------
__global__ __launch_bounds__(256) void gather_a_kernel(
    const float* __restrict__ h, const int* __restrict__ meta, u16* __restrict__ A) {
    const int row = blockIdx.x;
    const int tid = threadIdx.x;
    const int tok = meta[M_RTOK + row];
    u16* dst = A + (size_t)row * 1024;
    if (tok < 0) {
        uint2 z; z.x = 0u; z.y = 0u;
        ((uint2*)dst)[tid] = z;
        return;
    }
    const float wv = ((const float*)&meta[M_RW])[row];
    float4 v = ((const float4*)(h + (size_t)tok * 1024))[tid];
    u16 o[4] = { f2bf(v.x * wv), f2bf(v.y * wv), f2bf(v.z * wv), f2bf(v.w * wv) };
    ((uint2*)dst)[tid] = *(const uint2*)o;
}

// ---------------------------------------------------------------------------
// Kernel 4: grouped GEMM1 — up[base..base+128)[4096] = A_rows @ Wi[e]
//   A: bf16 [5120][1024], async swizzled staging (global chunk permuted so
//      linear lane->LDS mapping yields XOR-swizzled tile; conflict-free b128)
//   B: Wi[e] fp32 [1024][4096] natural layout, VGPR roundtrip + f2bf,
//      swizzled LDS store (round-4 proven, 0 conflicts)
//   Output raw fp32 (relu^2 must come AFTER cross-expert sum)
// ---------------------------------------------------------------------------
__global__ __launch_bounds__(256) void gemm1_sparse_kernel(
    const u16* __restrict__ A, const float* __restrict__ Wi,
    float* __restrict__ up, const int* __restrict__ meta) {
    const int mt = blockIdx.y;
    if (mt >= meta[M_NMT]) return;
    const int e = meta[M_TE + mt];
    const int base = meta[M_TB + mt];
    const int n0 = blockIdx.x * 128;
    const int K = 1024, N = 4096;
    const float* Bm = Wi + (size_t)e * K * N;

    __shared__ short a_tile[128 * 64];
    __shared__ short b_tile[128 * 64];
    const int tid = threadIdx.x;
    const int lane = tid & 63;
    const int wave = tid >> 6;
    const int wm = (wave >> 1) * 64;
    const int wn = (wave & 1) * 64;
    const int r = lane & 15;
    const int quad = lane >> 4;
    const int rowin = lane >> 3;
    const int achk = ((lane & 7) ^ (rowin & 7)) * 8;   // permuted global chunk
    const int aldst = (lane & 7) * 8;                  // linear LDS chunk

    const f32x4 vzero = {0.f, 0.f, 0.f, 0.f};
    f32x4 acc[4][4];
#pragma unroll
    for (int i = 0; i < 4; ++i)
#pragma unroll
        for (int j = 0; j < 4; ++j) acc[i][j] = vzero;

    for (int kb = 0; kb < K; kb += 64) {
        // B global loads (overlap prior MFMA)
        float bv[4][8];
#pragma unroll
        for (int cb = 0; cb < 4; ++cb) {
            int idx = cb * 256 + tid;
            int bn_ = idx & 127;
            int bk8 = idx >> 7;
            const float* bp = Bm + (size_t)(kb + bk8 * 8) * N + n0 + bn_;
#pragma unroll
            for (int kk = 0; kk < 8; ++kk) bv[cb][kk] = bp[(size_t)kk * N];
        }
        __syncthreads();   // prior iteration's LDS reads complete
        // A: async swizzled staging
#pragma unroll
        for (int it = 0; it < 4; ++it) {
            int row = wave * 8 + it * 32 + rowin;
            const u16* ga = A + (size_t)(base + row) * K + kb + achk;
            __builtin_amdgcn_global_load_lds(GLOBAL_AS(ga), LDS_AS(&a_tile[row * 64 + aldst]), 16, 0, 0);
        }
        // B: convert + swizzled LDS store
#pragma unroll
        for (int cb = 0; cb < 4; ++cb) {
            int idx = cb * 256 + tid;
            int bn_ = idx & 127;
            int bk8 = idx >> 7;
            u16 bc[8];
#pragma unroll
            for (int kk = 0; kk < 8; ++kk) bc[kk] = f2bf(bv[cb][kk]);
            *(short8_t*)&b_tile[bn_ * 64 + ((bk8 ^ (bn_ & 7)) * 8)] = *(const short8_t*)bc;
        }
        __syncthreads();
#pragma unroll
        for (int ks = 0; ks < 2; ++ks) {
            const int cp = ((ks * 4 + quad) ^ (r & 7)) * 8;
            short8_t af[4], bfr[4];
#pragma unroll
            for (int i = 0; i < 4; ++i)
                af[i] = *(const short8_t*)&a_tile[(wm + i * 16 + r) * 64 + cp];
#pragma unroll
            for (int j = 0; j < 4; ++j)
                bfr[j] = *(const short8_t*)&b_tile[(wn + j * 16 + r) * 64 + cp];
#pragma unroll
            for (int i = 0; i < 4; ++i)
#pragma unroll
                for (int j = 0; j < 4; ++j)
                    acc[i][j] = __builtin_amdgcn_mfma_f32_16x16x32_bf16(af[i], bfr[j], acc[i][j], 0, 0, 0);
        }
        __syncthreads();
    }
    // epilogue: raw fp32 (C/D layout col=lane&15, row=quad*4+reg)
#pragma unroll
    for (int i = 0; i < 4; ++i)
#pragma unroll
        for (int j = 0; j < 4; ++j)
#pragma unroll
            for (int reg = 0; reg < 4; ++reg) {
                int cr = base + wm + i * 16 + quad * 4 + reg;
                int cc = n0 + wn + j * 16 + r;
                up[(size_t)cr * N + cc] = acc[i][j][reg];
            }
}

// ---------------------------------------------------------------------------
// Kernel 5: combine — act[t] = bf16(relu^2(up[p0(t)] + up[p1(t)]))
// ---------------------------------------------------------------------------
__global__ __launch_bounds__(256) void combine_kernel(
    const float* __restrict__ up, const int* __restrict__ meta, u16* __restrict__ act) {
    const int t = blockIdx.x;
    const int tid = threadIdx.x;
    const int p0 = meta[M_PAIR + t * 2];
    const int p1 = meta[M_PAIR + t * 2 + 1];
    const float* r0 = up + (size_t)p0 * 4096;
    const float* r1 = up + (size_t)p1 * 4096;
    u16* dst = act + (size_t)t * 4096;
#pragma unroll
    for (int it = 0; it < 4; ++it) {
        int i = (tid + it * 256) * 4;
        float4 a = *(const float4*)&r0[i];
        float4 b = *(const float4*)&r1[i];
        float s0 = a.x + b.x, s1 = a.y + b.y, s2 = a.z + b.z, s3 = a.w + b.w;
        s0 = s0 > 0.f ? s0 * s0 : 0.f;
        s1 = s1 > 0.f ? s1 * s1 : 0.f;
        s2 = s2 > 0.f ? s2 * s2 : 0.f;
        s3 = s3 > 0.f ? s3 * s3 : 0.f;
        u16 o[4] = { f2bf(s0), f2bf(s1), f2bf(s2), f2bf(s3) };
        *(uint2*)&dst[i] = *(const uint2*)o;
    }
}

// ---------------------------------------------------------------------------
// Kernel T: transpose + fp32->bf16  in[R][C] fp32 -> out[C][R] bf16
// ---------------------------------------------------------------------------
__global__ __launch_bounds__(256) void transpose_cvt_kernel(
    const float* __restrict__ in, u16* __restrict__ out, int R, int C) {
    __shared__ u16 tile[64][65];
    const int rt = blockIdx.y * 64;
    const int ct = blockIdx.x * 64;
    const int tid = threadIdx.x;
#pragma unroll
    for (int it = 0; it < 2; ++it) {
        int r = (tid >> 3) + it * 32;
        int c8 = (tid & 7) * 8;
        const float* ip = &in[(size_t)(rt + r) * C + ct + c8];
        float4 v0 = *(const float4*)ip;
        float4 v1 = *(const float4*)(ip + 4);
        tile[c8 + 0][r] = f2bf(v0.x); tile[c8 + 1][r] = f2bf(v0.y);
        tile[c8 + 2][r] = f2bf(v0.z); tile[c8 + 3][r] = f2bf(v0.w);
        tile[c8 + 4][r] = f2bf(v1.x); tile[c8 + 5][r] = f2bf(v1.y);
        tile[c8 + 6][r] = f2bf(v1.z); tile[c8 + 7][r] = f2bf(v1.w);
    }
    __syncthreads();
#pragma unroll
    for (int it = 0; it < 2; ++it) {
        int c = (tid >> 3) + it * 32;
        int r8 = (tid & 7) * 8;
        u16 tmp[8];
#pragma unroll
        for (int j = 0; j < 8; ++j) tmp[j] = tile[c][r8 + j];
        *(uint4*)&out[(size_t)(ct + c) * R + rt + r8] = *(const uint4*)tmp;
    }
}

// ---------------------------------------------------------------------------
// Kernel 6: GEMM2 TN — C[M][N] fp32 = X[M][K] @ Y^T, both bf16 [row][K],
// async swizzled staging both sides, conflict-free b128 frag reads.
// BM x 128 tile, BK=64.
// ---------------------------------------------------------------------------
template <int BM, int WROWS, int WCOLS>
__global__ __launch_bounds__(256) void gemm_tn_kernel(
    const u16* __restrict__ X, const u16* __restrict__ Y, float* __restrict__ Cout,
    int M, int N, int K) {
    constexpr int WM = BM / WROWS;
    constexpr int WN = 128 / WCOLS;
    constexpr int FI = WM / 16;
    constexpr int FJ = WN / 16;
    __shared__ short a_tile[BM * 64];
    __shared__ short b_tile[128 * 64];
    const int tid = threadIdx.x;
    const int lane = tid & 63;
    const int wave = tid >> 6;

    // XCD-aware remap: same n_tile -> same XCD; m_tile varies fastest.
    const int Nt = gridDim.x, Mt = gridDim.y;
    const int lid = blockIdx.y * Nt + blockIdx.x;
    const int xcd = lid & 7;
    const int p = lid >> 3;
    const int n_tile = xcd * (Nt >> 3) + p / Mt;
    const int m_tile = p % Mt;
    const int m0 = m_tile * BM;
    const int n0 = n_tile * 128;

    const int wm = (wave / WCOLS) * WM;
    const int wn = (wave % WCOLS) * WN;
    const int rowin = lane >> 3;
    const int achk = ((lane & 7) ^ (rowin & 7)) * 8;
    const int aldst = (lane & 7) * 8;
    const int r = lane & 15;
    const int quad = lane >> 4;

    const f32x4 vzero = {0.f, 0.f, 0.f, 0.f};
    f32x4 acc[FI][FJ];
#pragma unroll
    for (int i = 0; i < FI; ++i)
#pragma unroll
        for (int j = 0; j < FJ; ++j) acc[i][j] = vzero;

    for (int kb = 0; kb < K; kb += 64) {
#pragma unroll
        for (int it = 0; it < BM / 32; ++it) {
            int row = wave * 8 + it * 32 + rowin;
            const u16* ga = X + (size_t)(m0 + row) * K + kb + achk;
            __builtin_amdgcn_global_load_lds(GLOBAL_AS(ga), LDS_AS(&a_tile[row * 64 + aldst]), 16, 0, 0);
        }
#pragma unroll
        for (int it = 0; it < 4; ++it) {
            int row = wave * 8 + it * 32 + rowin;
            const u16* gb = Y + (size_t)(n0 + row) * K + kb + achk;
            __builtin_amdgcn_global_load_lds(GLOBAL_AS(gb), LDS_AS(&b_tile[row * 64 + aldst]), 16, 0, 0);
        }
        __syncthreads();
#pragma unroll
        for (int ks = 0; ks < 2; ++ks) {
            const int cp = ((ks * 4 + quad) ^ (r & 7)) * 8;
            short8_t af[FI], bfr[FJ];
#pragma unroll
            for (int i = 0; i < FI; ++i)
                af[i] = *(const short8_t*)&a_tile[(wm + i * 16 + r) * 64 + cp];
#pragma unroll
            for (int j = 0; j < FJ; ++j)
                bfr[j] = *(const short8_t*)&b_tile[(wn + j * 16 + r) * 64 + cp];
#pragma unroll
            for (int i = 0; i < FI; ++i)
#pragma unroll
                for (int j = 0; j < FJ; ++j)
                    acc[i][j] = __builtin_amdgcn_mfma_f32_16x16x32_bf16(af[i], bfr[j], acc[i][j], 0, 0, 0);
        }
        __syncthreads();
    }
#pragma unroll
    for (int i = 0; i < FI; ++i)
#pragma unroll
        for (int j = 0; j < FJ; ++j)
#pragma unroll
            for (int reg = 0; reg < 4; ++reg) {
                int cr = m0 + wm + i * 16 + quad * 4 + reg;
                int cc = n0 + wn + j * 16 + r;
                Cout[(size_t)cr * N + cc] = acc[i][j][reg];
            }
}

// ---------------------------------------------------------------------------
// Launch
// ---------------------------------------------------------------------------
extern "C" void kernel_launch(void* const* d_in, const int* in_sizes, int n_in,
                              void* d_out, int out_size, void* d_ws, size_t ws_size,
                              hipStream_t stream) {
    const float* h    = (const float*)d_in[0];   // [2048][1024]
    const float* WG   = (const float*)d_in[1];   // [1024][8]
    const float* Wi   = (const float*)d_in[2];   // [8][1024][4096]
    const float* down = (const float*)d_in[3];   // [4096][1024]
    float* out = (float*)d_out;                  // [2048][1024]

    const int T = 2048, H = 1024, I = 4096;

    // workspace layout (~114.1 MiB; proven available >= 120.06 MiB)
    char* ws = (char*)d_ws;
    float* w_gate = (float*)(ws);                      // 64 KiB
    int*   meta   = (int*)(ws + 65536);                // 64 KiB
    u16*   Arow   = (u16*)(ws + 131072);               // 5120*1024*2 = 10 MiB
    float* up     = (float*)(ws + 131072 + 10485760);  // 5120*4096*4 = 80 MiB
    u16*   act    = (u16*)(ws + 131072 + 10485760 + 83886080);            // 16 MiB
    u16*   downT  = (u16*)(ws + 131072 + 10485760 + 83886080 + 16777216); // 8 MiB

    gate_topk_kernel<<<T, 64, 0, stream>>>(h, WG, w_gate);
    scan_kernel<<<1, 256, 0, stream>>>(w_gate, meta);
    gather_a_kernel<<<5120, 256, 0, stream>>>(h, meta, Arow);

    // grouped GEMM1: up to 40 m-tiles x 32 n-tiles; raw fp32 out
    gemm1_sparse_kernel<<<dim3(32, 40), 256, 0, stream>>>(Arow, Wi, up, meta);

    // combine pairs + relu^2 -> dense act bf16 [2048][4096]
    combine_kernel<<<T, 256, 0, stream>>>(up, meta, act);

    // down^T bf16, then GEMM2 TN -> fp32 out
    transpose_cvt_kernel<<<dim3(H / 64, I / 64), 256, 0, stream>>>(down, downT, I, H);
    gemm_tn_kernel<64, 1, 4><<<dim3(H / 128, T / 64), 256, 0, stream>>>(
        act, downT, out, T, H, I);
}